// Round 2
// baseline (2954.446 us; speedup 1.0000x reference)
//
#include <hip/hip_runtime.h>
#include <hip/hip_bf16.h>

// SocialLSTM forward, MI355X gfx950.
// Dual-dtype: float inputs may be bf16 or f32; detected at runtime from W_soc.
// ws layout (bytes):
//   h_ws  f32[1024*64]      @ 0
//   c_ws  f32[1024*64]      @ 262144
//   Wt2   bf16[64][256][64] @ 1835008   (W_soc cell-major: [cell][n][k], 8 MB)
//   flag  int32             @ 11141120  (0 = bf16 inputs, 1 = f32 inputs)
//   part  f32[16][1024*256] @ 16777216  (K-split GEMM partials, no atomics)
//   r_all f32[32][1024][64] @ 33554432  (precomputed r = relu(coords@Wemb+b))
//   offs  u16[32*1024][64]  @ 41943040  (per (t,i): 50 prefix offsets of cell lists)
//   ents  u16[32*1024][1024]@ 50331648  (per (t,i): compacted neighbor j-lists)

typedef short bf16x8 __attribute__((ext_vector_type(8)));
typedef float f32x4 __attribute__((ext_vector_type(4)));

__device__ __forceinline__ float u2f(unsigned short u) {
    union { unsigned int i; float f; } v; v.i = ((unsigned int)u) << 16; return v.f;
}
__device__ __forceinline__ unsigned short f2b(float f) {
    __hip_bfloat16 hb = __float2bfloat16(f);
    return *(unsigned short*)&hb;
}
__device__ __forceinline__ float ldin(const void* p, int idx, int isf32) {
    return isf32 ? ((const float*)p)[idx] : u2f(((const unsigned short*)p)[idx]);
}
__device__ __forceinline__ int get_tpred(const int* p) {
    int v = p[0];
    if (v >= 0 && v <= 64) return v;
    float f = ((const float*)p)[0];
    if (f >= 0.f && f <= 64.f) return (int)f;
    float g = u2f(((const unsigned short*)p)[0]);
    if (g >= 0.f && g <= 64.f) return (int)g;
    return 31;
}

// ---------------- dtype detector: bf16-decode W_soc, look for huge/NaN -----
__global__ __launch_bounds__(256) void k_detect(const void* __restrict__ Wsoc,
                                                int* __restrict__ flag) {
    __shared__ int f;
    int tid = threadIdx.x;
    if (tid == 0) f = 0;
    __syncthreads();
    const unsigned short* p = (const unsigned short*)Wsoc;
    #pragma unroll
    for (int k = 0; k < 4; k++) {
        float v = u2f(p[tid * 4 + k]);
        if (!(v == v) || fabsf(v) > 1e20f) f = 1;   // same-address LDS write, benign
    }
    __syncthreads();
    if (tid == 0) flag[0] = f;
}

// ------- one-time: W_soc (4096x256) -> Wt2 bf16 cell-major [cell][n][k] ----
__global__ __launch_bounds__(256) void k_transpose(const void* __restrict__ Wsoc,
                                                   unsigned short* __restrict__ Wt2,
                                                   const int* __restrict__ flag) {
    __shared__ __align__(16) unsigned short tile[32 * 264];
    int isf32 = flag[0];
    int b = blockIdx.x, tid = threadIdx.x;
    int k0 = b * 32;
    if (isf32) {
        const float* W = (const float*)Wsoc;
        #pragma unroll
        for (int p = 0; p < 4; p++) {
            int kk = (tid >> 5) + p * 8;
            int n8 = (tid & 31) * 8;
            #pragma unroll
            for (int q = 0; q < 8; q++)
                tile[kk * 264 + n8 + q] = f2b(W[(k0 + kk) * 256 + n8 + q]);
        }
    } else {
        const unsigned short* W = (const unsigned short*)Wsoc;
        #pragma unroll
        for (int p = 0; p < 4; p++) {
            int kk = (tid >> 5) + p * 8;
            int n8 = (tid & 31) * 8;
            *(uint4*)&tile[kk * 264 + n8] = *(const uint4*)(W + (k0 + kk) * 256 + n8);
        }
    }
    __syncthreads();
    int n = tid;
    unsigned int packed[16];
    #pragma unroll
    for (int q = 0; q < 16; q++) {
        unsigned int lo = tile[(2 * q) * 264 + n];
        unsigned int hi = tile[(2 * q + 1) * 264 + n];
        packed[q] = lo | (hi << 16);
    }
    int craw = k0 >> 6, kk0 = k0 & 63;
    uint4* dst = (uint4*)(Wt2 + (long)craw * 16384 + (long)n * 64 + kk0);
    #pragma unroll
    for (int p = 0; p < 4; p++)
        dst[p] = make_uint4(packed[4*p], packed[4*p+1], packed[4*p+2], packed[4*p+3]);
}

// ---------------- one-time: zero d_out (dtype-sized), h0/c0 -> f32 ---------
__global__ __launch_bounds__(256) void k_init(void* __restrict__ out,
                                              const void* __restrict__ hin,
                                              const void* __restrict__ cin,
                                              float* __restrict__ h_ws,
                                              float* __restrict__ c_ws,
                                              const int* __restrict__ flag) {
    int isf32 = flag[0];
    int b = blockIdx.x, tid = threadIdx.x;
    if (b < 16) {
        uint4 z = make_uint4(0u, 0u, 0u, 0u);
        uint4* p = (uint4*)out;
        int n16 = isf32 ? 16384 : 8192;          // 65536 elems * 4 or 2 bytes / 16
        for (int idx = b * 256 + tid; idx < n16; idx += 4096) p[idx] = z;
    } else {
        int sb = b - 16;
        const void* src = (sb < 16) ? hin : cin;
        float* dst = (sb < 16) ? h_ws : c_ws;
        sb &= 15;
        int base = (sb * 256 + tid) * 16;
        #pragma unroll
        for (int p = 0; p < 16; p++) dst[base + p] = ldin(src, base + p, isf32);
    }
}

// ---------------- one-time: codes via LDS-atomic ranks + r_all -------------
// grid 32*1024 blocks: t = bid>>10, i = bid&1023. Replaces 2-pass ballot
// compaction (400+ ballot/popc per thread) with 4 LDS atomics + scatter.
__global__ __launch_bounds__(256) void k_codes(const void* __restrict__ X,
                                               const int* __restrict__ masks,
                                               const void* __restrict__ Wemb,
                                               const void* __restrict__ bemb,
                                               const int* __restrict__ Tpred,
                                               const int* __restrict__ flag,
                                               float* __restrict__ r_all,
                                               unsigned short* __restrict__ offs,
                                               unsigned short* __restrict__ ents) {
    int bid = blockIdx.x;
    int t = bid >> 10, i = bid & 1023;
    if (t > get_tpred(Tpred)) return;
    int isf32 = flag[0];
    int tid = threadIdx.x;
    __shared__ int cnt[49];
    __shared__ unsigned short off_s[52];
    float cix, ciy;
    if (isf32) {
        const float* Xf = (const float*)X;
        cix = Xf[(t * 1024 + i) * 4 + 2];
        ciy = Xf[(t * 1024 + i) * 4 + 3];
    } else {
        const unsigned short* Xb = (const unsigned short*)X;
        cix = u2f(Xb[(t * 1024 + i) * 4 + 2]);
        ciy = u2f(Xb[(t * 1024 + i) * 4 + 3]);
    }
    if (tid < 64) {
        float v = ldin(Wemb, tid, isf32) * cix + ldin(Wemb, 64 + tid, isf32) * ciy
                + ldin(bemb, tid, isf32);
        r_all[((long)t * 1024 + i) * 64 + tid] = fmaxf(v, 0.f);
    }
    if (masks[t * 1024 + i] == 0) return;     // block-uniform; lists unused
    if (tid < 49) cnt[tid] = 0;
    __syncthreads();
    int cc[4], rk[4];
    #pragma unroll
    for (int p = 0; p < 4; p++) {
        int j = tid + p * 256;
        cc[p] = -1;
        if (j != i && masks[t * 1024 + j] != 0) {
            float dx, dy;
            if (isf32) {
                const float* Xf = (const float*)X;
                dx = Xf[(t * 1024 + j) * 4 + 2] - cix;
                dy = Xf[(t * 1024 + j) * 4 + 3] - ciy;
            } else {
                const unsigned short* Xb = (const unsigned short*)X;
                dx = u2f(Xb[(t * 1024 + j) * 4 + 2]) - cix;
                dy = u2f(Xb[(t * 1024 + j) * 4 + 3]) - ciy;
            }
            int g0 = (int)dx, g1 = (int)dy;   // trunc toward zero == jnp.trunc
            if (g0 >= -3 && g0 <= 3 && g1 >= -3 && g1 <= 3) {
                int c = (g0 + 3) * 7 + (g1 + 3);      // dense 0..48
                cc[p] = c;
                rk[p] = atomicAdd(&cnt[c], 1);
            }
        }
    }
    __syncthreads();
    if (tid == 0) {
        int o = 0;
        #pragma unroll 1
        for (int c = 0; c < 49; c++) { off_s[c] = (unsigned short)o; o += cnt[c]; }
        off_s[49] = (unsigned short)o;
    }
    __syncthreads();
    unsigned short* eb = ents + ((long)t * 1024 + i) * 1024;
    #pragma unroll
    for (int p = 0; p < 4; p++)
        if (cc[p] >= 0)
            eb[off_s[cc[p]] + rk[p]] = (unsigned short)(tid + p * 256);
    if (tid < 50) offs[((long)t * 1024 + i) * 64 + tid] = off_s[tid];
}

// ------- per step: fused pool+GEMM. grid 256 = 16 rb x 16 s, 512 thr -------
// Block (rb,s): rows rb*64..+63, cells m0..m1 (3-4). Per cell: stage B tile
// (coalesced from cell-major Wt2), pool rows straight into the MFMA A-tile
// in LDS (dual-row interleaved gathers), 16 MFMA/wave, accumulate. Hbuf gone.
__global__ __launch_bounds__(512) void k_pg(const int* __restrict__ masks,
                                            const int* __restrict__ Tpred,
                                            const float* __restrict__ h_ws,
                                            const unsigned short* __restrict__ offs,
                                            const unsigned short* __restrict__ ents,
                                            const unsigned short* __restrict__ Wt2,
                                            float* __restrict__ part,
                                            int t) {
    if (t > get_tpred(Tpred)) return;
    int bid = blockIdx.x, tid = threadIdx.x;
    int s = bid & 15, rb = bid >> 4;
    int row0 = rb * 64;
    int m0 = (49 * s) >> 4, m1 = (49 * (s + 1)) >> 4;   // 3 or 4 cells
    __shared__ __align__(16) short Asm[64 * 72];        // 9 KB
    __shared__ __align__(16) short Bsm[256 * 72];       // 36 KB
    __shared__ unsigned short offsL[64][6];
    __shared__ int maskL[64];
    int w = tid >> 6, lane = tid & 63;
    int mrow = lane & 15, qq = lane >> 4;
    if (tid < 64) maskL[tid] = masks[t * 1024 + row0 + tid];
    {
        int nof = m1 - m0 + 1;                          // 4 or 5
        for (int idx = tid; idx < 64 * nof; idx += 512) {
            int r = idx / nof, q = idx - r * nof;
            offsL[r][q] = offs[((long)t * 1024 + row0 + r) * 64 + m0 + q];
        }
    }
    f32x4 acc[4][2];
    f32x4 zz = {0.f, 0.f, 0.f, 0.f};
    #pragma unroll
    for (int a = 0; a < 4; a++) { acc[a][0] = zz; acc[a][1] = zz; }
    for (int m = m0; m < m1; m++) {
        __syncthreads();   // prev-cell MFMA readers done; (1st iter: offs/mask ready)
        // stage B tile: 2048 uint4, coalesced from cell-major Wt2
        {
            int craw = (m / 7) * 8 + (m % 7) + 9;
            const uint4* bsrc = (const uint4*)(Wt2 + (long)craw * 16384);
            #pragma unroll
            for (int u = 0; u < 4; u++) {
                int i4 = tid + u * 512;
                int n = i4 >> 3, sg = i4 & 7;
                *(uint4*)&Bsm[n * 72 + sg * 8] = bsrc[i4];
            }
        }
        // pool 8 rows/wave for cell m, dual-row interleaved for load overlap
        int q = m - m0;
        #pragma unroll 1
        for (int rr = 0; rr < 4; rr++) {
            int rA = w * 8 + 2 * rr, rB = rA + 1;
            int oA = 0, eA = 0, oB = 0, eB = 0;
            if (maskL[rA]) { oA = offsL[rA][q]; eA = offsL[rA][q + 1]; }
            if (maskL[rB]) { oB = offsL[rB][q]; eB = offsL[rB][q + 1]; }
            const unsigned short* ebA = ents + ((long)t * 1024 + row0 + rA) * 1024;
            const unsigned short* ebB = ents + ((long)t * 1024 + row0 + rB) * 1024;
            float aA = 0.f, aB = 0.f;
            int kA = oA, kB = oB;
            while (kA + 8 <= eA && kB + 8 <= eB) {
                int ja[8], jb[8];
                #pragma unroll
                for (int u = 0; u < 8; u++) { ja[u] = ebA[kA + u]; jb[u] = ebB[kB + u]; }
                float sa = 0.f, sb = 0.f;
                #pragma unroll
                for (int u = 0; u < 8; u++) {
                    sa += h_ws[ja[u] * 64 + lane];
                    sb += h_ws[jb[u] * 64 + lane];
                }
                aA += sa; aB += sb; kA += 8; kB += 8;
            }
            for (; kA + 8 <= eA; kA += 8) {
                int ja[8];
                #pragma unroll
                for (int u = 0; u < 8; u++) ja[u] = ebA[kA + u];
                float sa = 0.f;
                #pragma unroll
                for (int u = 0; u < 8; u++) sa += h_ws[ja[u] * 64 + lane];
                aA += sa;
            }
            for (; kB + 8 <= eB; kB += 8) {
                int jb[8];
                #pragma unroll
                for (int u = 0; u < 8; u++) jb[u] = ebB[kB + u];
                float sb = 0.f;
                #pragma unroll
                for (int u = 0; u < 8; u++) sb += h_ws[jb[u] * 64 + lane];
                aB += sb;
            }
            for (; kA < eA; kA++) aA += h_ws[ebA[kA] * 64 + lane];
            for (; kB < eB; kB++) aB += h_ws[ebB[kB] * 64 + lane];
            Asm[rA * 72 + lane] = f2b(aA);
            Asm[rB * 72 + lane] = f2b(aB);
        }
        __syncthreads();
        // MFMA: wave w owns cols w*32..+31 (2 ntiles), all 4 mtiles
        #pragma unroll
        for (int kc = 0; kc < 2; kc++) {
            bf16x8 av[4];
            #pragma unroll
            for (int mt = 0; mt < 4; mt++)
                av[mt] = *(bf16x8*)&Asm[(mt * 16 + mrow) * 72 + kc * 32 + qq * 8];
            #pragma unroll
            for (int nt = 0; nt < 2; nt++) {
                bf16x8 bv = *(bf16x8*)&Bsm[(w * 32 + nt * 16 + mrow) * 72 + kc * 32 + qq * 8];
                #pragma unroll
                for (int mt = 0; mt < 4; mt++)
                    acc[mt][nt] = __builtin_amdgcn_mfma_f32_16x16x32_bf16(av[mt], bv, acc[mt][nt], 0, 0, 0);
            }
        }
    }
    // C/D layout: col = lane&15, row = (lane>>4)*4 + reg. Plain stores, no RMW.
    float* ps = part + (long)s * 262144;
    #pragma unroll
    for (int mt = 0; mt < 4; mt++)
        #pragma unroll
        for (int nt = 0; nt < 2; nt++)
            #pragma unroll
            for (int r = 0; r < 4; r++) {
                int grow = row0 + mt * 16 + qq * 4 + r;
                int gcol = w * 32 + nt * 16 + mrow;
                ps[grow * 256 + gcol] = acc[mt][nt][r];
            }
}

// ---------------- per step: gates GEMV (8 rows/block), LSTM cell, out ------
// grid 128 x 512 threads: 8 rows/block, 2-way K-split. Weights read once per
// block (50 MB/step); zT broadcast-read from LDS.
__global__ __launch_bounds__(512) void k_cell(const int* __restrict__ masks,
                                              const void* __restrict__ Y,
                                              const void* __restrict__ bsoc,
                                              const void* __restrict__ Wih,
                                              const void* __restrict__ bih,
                                              const void* __restrict__ Whh,
                                              const void* __restrict__ bhh,
                                              const void* __restrict__ Wout,
                                              const void* __restrict__ bout,
                                              const int* __restrict__ Tpred,
                                              const int* __restrict__ flag,
                                              float* __restrict__ h_ws,
                                              float* __restrict__ c_ws,
                                              const float* __restrict__ r_all,
                                              const float* __restrict__ part,
                                              void* __restrict__ out,
                                              int t) {
    if (t > get_tpred(Tpred)) return;
    int isf32 = flag[0];
    int tid = threadIdx.x;
    int r0 = blockIdx.x * 8;
    __shared__ __align__(32) float zT[384][8];   // z transposed: [k][local row]
    __shared__ float g2[2][8][256];              // K-split partial gates
    // phase A: build zT = [r | e | h] for the block's 8 rows
    for (int idx = tid; idx < 3072; idx += 512) {
        int r = idx / 384, k = idx - r * 384;
        int grow = r0 + r;
        float v;
        if (k < 64) {
            v = r_all[((long)t * 1024 + grow) * 64 + k];
        } else if (k < 320) {
            int col = k - 64;
            const float* pp = part + grow * 256 + col;
            float s0 = 0.f, s1 = 0.f, s2 = 0.f, s3 = 0.f;
            #pragma unroll
            for (int ss = 0; ss < 4; ss++) {
                s0 += pp[(ss * 4 + 0) * 262144];
                s1 += pp[(ss * 4 + 1) * 262144];
                s2 += pp[(ss * 4 + 2) * 262144];
                s3 += pp[(ss * 4 + 3) * 262144];
            }
            v = fmaxf(ldin(bsoc, col, isf32) + ((s0 + s1) + (s2 + s3)), 0.f);
        } else {
            v = h_ws[grow * 64 + (k - 320)];
        }
        zT[k][r] = v;
    }
    __syncthreads();
    // phase B: partial gates; each weight element loaded exactly once per block
    int kh = tid >> 8, col = tid & 255;
    float a0 = 0.f, a1 = 0.f, a2 = 0.f, a3 = 0.f,
          a4 = 0.f, a5 = 0.f, a6 = 0.f, a7 = 0.f;
    int klo = kh ? 192 : 0, khi = kh ? 384 : 192;
    #pragma unroll 2
    for (int k = klo; k < khi; k++) {
        float wv;
        if (isf32) {
            wv = (k < 320) ? ((const float*)Wih)[(long)k * 256 + col]
                           : ((const float*)Whh)[(long)(k - 320) * 256 + col];
        } else {
            wv = (k < 320) ? u2f(((const unsigned short*)Wih)[(long)k * 256 + col])
                           : u2f(((const unsigned short*)Whh)[(long)(k - 320) * 256 + col]);
        }
        f32x4 z0 = *(f32x4*)&zT[k][0];
        f32x4 z1 = *(f32x4*)&zT[k][4];
        a0 += z0[0] * wv; a1 += z0[1] * wv; a2 += z0[2] * wv; a3 += z0[3] * wv;
        a4 += z1[0] * wv; a5 += z1[1] * wv; a6 += z1[2] * wv; a7 += z1[3] * wv;
    }
    g2[kh][0][col] = a0; g2[kh][1][col] = a1; g2[kh][2][col] = a2; g2[kh][3][col] = a3;
    g2[kh][4][col] = a4; g2[kh][5][col] = a5; g2[kh][6][col] = a6; g2[kh][7][col] = a7;
    __syncthreads();
    // phase C: fold K-split halves + biases
    if (tid < 256) {
        float bb = ldin(bih, tid, isf32) + ldin(bhh, tid, isf32);
        #pragma unroll
        for (int r = 0; r < 8; r++)
            g2[0][r][tid] = g2[0][r][tid] + g2[1][r][tid] + bb;
    }
    __syncthreads();
    // phase D: LSTM cell + output (8 rows x 64 lanes)
    {
        int row = tid >> 6, u = tid & 63;
        int grow = r0 + row;
        float gi = g2[0][row][u];
        float gf = g2[0][row][64 + u];
        float gg = g2[0][row][128 + u];
        float go = g2[0][row][192 + u];
        float c  = c_ws[grow * 64 + u];
        float si = 1.f / (1.f + __expf(-gi));
        float sf = 1.f / (1.f + __expf(-gf));
        float so = 1.f / (1.f + __expf(-go));
        float cn = sf * c + si * tanhf(gg);
        float hn = so * tanhf(cn);
        c_ws[grow * 64 + u] = cn;
        h_ws[grow * 64 + u] = hn;
        float p0 = hn * ldin(Wout, u * 2 + 0, isf32);
        float p1 = hn * ldin(Wout, u * 2 + 1, isf32);
        #pragma unroll
        for (int o = 32; o >= 1; o >>= 1) {
            p0 += __shfl_xor(p0, o);
            p1 += __shfl_xor(p1, o);
        }
        if (u == 0) {
            int m = masks[t * 1024 + grow];
            float o0 = 0.f, o1 = 0.f;
            if (m != 0) {
                bool appear = (t > 3) && (masks[(t - 3) * 1024 + grow] == 0);
                if (appear) {
                    o0 = ldin(Y, (t * 1024 + grow) * 2 + 0, isf32);
                    o1 = ldin(Y, (t * 1024 + grow) * 2 + 1, isf32);
                } else {
                    o0 = p0 + ldin(bout, 0, isf32);
                    o1 = p1 + ldin(bout, 1, isf32);
                }
            }
            if (!(o0 == o0)) o0 = 0.f;            // sanitize: finite diagnostics
            if (!(o1 == o1)) o1 = 0.f;
            int ofs = (t * 1024 + grow) * 2;
            if (isf32) {
                ((float*)out)[ofs + 0] = o0;
                ((float*)out)[ofs + 1] = o1;
            } else {
                ((unsigned short*)out)[ofs + 0] = f2b(o0);
                ((unsigned short*)out)[ofs + 1] = f2b(o1);
            }
        }
    }
}

extern "C" void kernel_launch(void* const* d_in, const int* in_sizes, int n_in,
                              void* d_out, int out_size, void* d_ws, size_t ws_size,
                              hipStream_t stream) {
    (void)in_sizes; (void)n_in; (void)out_size; (void)ws_size;
    const void* X     = d_in[0];
    const int*  masks = (const int*)d_in[1];
    const void* h0    = d_in[2];
    const void* c0    = d_in[3];
    const void* Y     = d_in[4];
    // d_in[5] = T_obs (unused by reference)
    const int*  Tpred = (const int*)d_in[6];
    const void* Wemb  = d_in[7];
    const void* bemb  = d_in[8];
    const void* Wsoc  = d_in[9];
    const void* bsoc  = d_in[10];
    const void* Wih   = d_in[11];
    const void* bih   = d_in[12];
    const void* Whh   = d_in[13];
    const void* bhh   = d_in[14];
    const void* Wout  = d_in[15];
    const void* bout  = d_in[16];

    char* ws = (char*)d_ws;
    float*          h_ws  = (float*)(ws + 0);
    float*          c_ws  = (float*)(ws + 262144);
    unsigned short* Wt2   = (unsigned short*)(ws + 1835008);
    int*            flag  = (int*)(ws + 11141120);
    float*          part  = (float*)(ws + 16777216);
    float*          r_all = (float*)(ws + 33554432);
    unsigned short* offs  = (unsigned short*)(ws + 41943040);
    unsigned short* ents  = (unsigned short*)(ws + 50331648);

    k_detect<<<1, 256, 0, stream>>>(Wsoc, flag);
    k_transpose<<<128, 256, 0, stream>>>(Wsoc, Wt2, flag);
    k_init<<<48, 256, 0, stream>>>(d_out, h0, c0, h_ws, c_ws, flag);
    k_codes<<<32768, 256, 0, stream>>>(X, masks, Wemb, bemb, Tpred, flag,
                                       r_all, offs, ents);
    for (int t = 0; t < 32; t++) {
        k_pg<<<256, 512, 0, stream>>>(masks, Tpred, h_ws, offs, ents, Wt2, part, t);
        k_cell<<<128, 512, 0, stream>>>(masks, Y, bsoc, Wih, bih, Whh, bhh,
                                        Wout, bout, Tpred, flag, h_ws, c_ws,
                                        r_all, part, d_out, t);
    }
}

// Round 3
// 1886.153 us; speedup vs baseline: 1.5664x; 1.5664x over previous
//
#include <hip/hip_runtime.h>
#include <hip/hip_bf16.h>

// SocialLSTM forward, MI355X gfx950.
// Dual-dtype: float inputs may be bf16 or f32; detected at runtime from W_soc.
// ws layout (bytes):
//   h_ws  f32[1024*64]      @ 0
//   c_ws  f32[1024*64]      @ 262144
//   Wt2   bf16[64][256][64] @ 1835008   (W_soc cell-major: [cell][n][k], 2 MB)
//   Hbuf  bf16[1024*3136]   @ 3932160   (49 reachable cells * 64 hid per row)
//   flag  int32             @ 11141120  (0 = bf16 inputs, 1 = f32 inputs)
//   part  f32[8][1024*256]  @ 16777216  (K-split GEMM partials, no atomics)
//   r_all f32[32][1024][64] @ 33554432  (precomputed r = relu(coords@Wemb+b))
//   offs  u16[32*1024][64]  @ 41943040  (per (t,i): 50 prefix offsets of cell lists)
//   ents  u16[32*1024][1024]@ 50331648  (per (t,i): compacted neighbor j-lists)

typedef short bf16x8 __attribute__((ext_vector_type(8)));
typedef float f32x4 __attribute__((ext_vector_type(4)));

__device__ __forceinline__ float u2f(unsigned short u) {
    union { unsigned int i; float f; } v; v.i = ((unsigned int)u) << 16; return v.f;
}
__device__ __forceinline__ unsigned short f2b(float f) {
    __hip_bfloat16 hb = __float2bfloat16(f);
    return *(unsigned short*)&hb;
}
__device__ __forceinline__ float ldin(const void* p, int idx, int isf32) {
    return isf32 ? ((const float*)p)[idx] : u2f(((const unsigned short*)p)[idx]);
}
__device__ __forceinline__ int get_tpred(const int* p) {
    int v = p[0];
    if (v >= 0 && v <= 64) return v;
    float f = ((const float*)p)[0];
    if (f >= 0.f && f <= 64.f) return (int)f;
    float g = u2f(((const unsigned short*)p)[0]);
    if (g >= 0.f && g <= 64.f) return (int)g;
    return 31;
}

// ---------------- dtype detector: bf16-decode W_soc, look for huge/NaN -----
__global__ __launch_bounds__(256) void k_detect(const void* __restrict__ Wsoc,
                                                int* __restrict__ flag) {
    __shared__ int f;
    int tid = threadIdx.x;
    if (tid == 0) f = 0;
    __syncthreads();
    const unsigned short* p = (const unsigned short*)Wsoc;
    #pragma unroll
    for (int k = 0; k < 4; k++) {
        float v = u2f(p[tid * 4 + k]);
        if (!(v == v) || fabsf(v) > 1e20f) f = 1;   // same-address LDS write, benign
    }
    __syncthreads();
    if (tid == 0) flag[0] = f;
}

// ------- one-time: W_soc (4096x256) -> Wt2 bf16 cell-major [cell][n][k] ----
__global__ __launch_bounds__(256) void k_transpose(const void* __restrict__ Wsoc,
                                                   unsigned short* __restrict__ Wt2,
                                                   const int* __restrict__ flag) {
    __shared__ __align__(16) unsigned short tile[32 * 264];
    int isf32 = flag[0];
    int b = blockIdx.x, tid = threadIdx.x;
    int k0 = b * 32;
    if (isf32) {
        const float* W = (const float*)Wsoc;
        #pragma unroll
        for (int p = 0; p < 4; p++) {
            int kk = (tid >> 5) + p * 8;
            int n8 = (tid & 31) * 8;
            #pragma unroll
            for (int q = 0; q < 8; q++)
                tile[kk * 264 + n8 + q] = f2b(W[(k0 + kk) * 256 + n8 + q]);
        }
    } else {
        const unsigned short* W = (const unsigned short*)Wsoc;
        #pragma unroll
        for (int p = 0; p < 4; p++) {
            int kk = (tid >> 5) + p * 8;
            int n8 = (tid & 31) * 8;
            *(uint4*)&tile[kk * 264 + n8] = *(const uint4*)(W + (k0 + kk) * 256 + n8);
        }
    }
    __syncthreads();
    int n = tid;
    unsigned int packed[16];
    #pragma unroll
    for (int q = 0; q < 16; q++) {
        unsigned int lo = tile[(2 * q) * 264 + n];
        unsigned int hi = tile[(2 * q + 1) * 264 + n];
        packed[q] = lo | (hi << 16);
    }
    int craw = k0 >> 6, kk0 = k0 & 63;
    uint4* dst = (uint4*)(Wt2 + (long)craw * 16384 + (long)n * 64 + kk0);
    #pragma unroll
    for (int p = 0; p < 4; p++)
        dst[p] = make_uint4(packed[4*p], packed[4*p+1], packed[4*p+2], packed[4*p+3]);
}

// ---------------- one-time: zero d_out (dtype-sized), h0/c0 -> f32 ---------
__global__ __launch_bounds__(256) void k_init(void* __restrict__ out,
                                              const void* __restrict__ hin,
                                              const void* __restrict__ cin,
                                              float* __restrict__ h_ws,
                                              float* __restrict__ c_ws,
                                              const int* __restrict__ flag) {
    int isf32 = flag[0];
    int b = blockIdx.x, tid = threadIdx.x;
    if (b < 16) {
        uint4 z = make_uint4(0u, 0u, 0u, 0u);
        uint4* p = (uint4*)out;
        int n16 = isf32 ? 16384 : 8192;          // 65536 elems * 4 or 2 bytes / 16
        for (int idx = b * 256 + tid; idx < n16; idx += 4096) p[idx] = z;
    } else {
        int sb = b - 16;
        const void* src = (sb < 16) ? hin : cin;
        float* dst = (sb < 16) ? h_ws : c_ws;
        sb &= 15;
        int base = (sb * 256 + tid) * 16;
        #pragma unroll
        for (int p = 0; p < 16; p++) dst[base + p] = ldin(src, base + p, isf32);
    }
}

// ---------------- one-time: codes via LDS-atomic ranks + r_all -------------
// grid 32*1024 blocks: t = bid>>10, i = bid&1023. 4 LDS atomics + scatter
// replaces the 2-pass ballot compaction (was 155 us VALU-bound).
__global__ __launch_bounds__(256) void k_codes(const void* __restrict__ X,
                                               const int* __restrict__ masks,
                                               const void* __restrict__ Wemb,
                                               const void* __restrict__ bemb,
                                               const int* __restrict__ Tpred,
                                               const int* __restrict__ flag,
                                               float* __restrict__ r_all,
                                               unsigned short* __restrict__ offs,
                                               unsigned short* __restrict__ ents) {
    int bid = blockIdx.x;
    int t = bid >> 10, i = bid & 1023;
    if (t > get_tpred(Tpred)) return;
    int isf32 = flag[0];
    int tid = threadIdx.x;
    __shared__ int cnt[49];
    __shared__ unsigned short off_s[52];
    float cix, ciy;
    if (isf32) {
        const float* Xf = (const float*)X;
        cix = Xf[(t * 1024 + i) * 4 + 2];
        ciy = Xf[(t * 1024 + i) * 4 + 3];
    } else {
        const unsigned short* Xb = (const unsigned short*)X;
        cix = u2f(Xb[(t * 1024 + i) * 4 + 2]);
        ciy = u2f(Xb[(t * 1024 + i) * 4 + 3]);
    }
    if (tid < 64) {
        float v = ldin(Wemb, tid, isf32) * cix + ldin(Wemb, 64 + tid, isf32) * ciy
                + ldin(bemb, tid, isf32);
        r_all[((long)t * 1024 + i) * 64 + tid] = fmaxf(v, 0.f);
    }
    if (masks[t * 1024 + i] == 0) return;     // block-uniform; lists unused
    if (tid < 49) cnt[tid] = 0;
    __syncthreads();
    int cc[4], rk[4];
    #pragma unroll
    for (int p = 0; p < 4; p++) {
        int j = tid + p * 256;
        cc[p] = -1;
        if (j != i && masks[t * 1024 + j] != 0) {
            float dx, dy;
            if (isf32) {
                const float* Xf = (const float*)X;
                dx = Xf[(t * 1024 + j) * 4 + 2] - cix;
                dy = Xf[(t * 1024 + j) * 4 + 3] - ciy;
            } else {
                const unsigned short* Xb = (const unsigned short*)X;
                dx = u2f(Xb[(t * 1024 + j) * 4 + 2]) - cix;
                dy = u2f(Xb[(t * 1024 + j) * 4 + 3]) - ciy;
            }
            int g0 = (int)dx, g1 = (int)dy;   // trunc toward zero == jnp.trunc
            if (g0 >= -3 && g0 <= 3 && g1 >= -3 && g1 <= 3) {
                int c = (g0 + 3) * 7 + (g1 + 3);      // dense 0..48
                cc[p] = c;
                rk[p] = atomicAdd(&cnt[c], 1);
            }
        }
    }
    __syncthreads();
    if (tid == 0) {
        int o = 0;
        #pragma unroll 1
        for (int c = 0; c < 49; c++) { off_s[c] = (unsigned short)o; o += cnt[c]; }
        off_s[49] = (unsigned short)o;
    }
    __syncthreads();
    unsigned short* eb = ents + ((long)t * 1024 + i) * 1024;
    #pragma unroll
    for (int p = 0; p < 4; p++)
        if (cc[p] >= 0)
            eb[off_s[cc[p]] + rk[p]] = (unsigned short)(tid + p * 256);
    if (tid < 50) offs[((long)t * 1024 + i) * 64 + tid] = off_s[tid];
}

// ---------------- per step: pure gather-accumulate pooling -> Hbuf ---------
// 1024 blocks (one per agent) keeps ~16 waves/CU of independent gather work
// in flight — this phase is latency-bound, parallelism is the currency.
__global__ __launch_bounds__(256) void k_pool(const int* __restrict__ masks,
                                              const int* __restrict__ Tpred,
                                              const float* __restrict__ h_ws,
                                              const unsigned short* __restrict__ offs,
                                              const unsigned short* __restrict__ ents,
                                              unsigned short* __restrict__ Hbuf,
                                              int t) {
    if (t > get_tpred(Tpred)) return;
    int i = blockIdx.x, tid = threadIdx.x;
    long hb_base = (long)i * 3136;
    if (masks[t * 1024 + i] == 0) {   // block-uniform: H row is all zeros
        unsigned int* hp = (unsigned int*)(Hbuf + hb_base);
        for (int idx = tid; idx < 1568; idx += 256) hp[idx] = 0u;
        return;
    }
    __shared__ __align__(16) unsigned short el[1024];
    __shared__ unsigned short of[52];
    if (tid < 50) of[tid] = offs[((long)t * 1024 + i) * 64 + tid];
    {
        const uint4* src = (const uint4*)(ents + ((long)t * 1024 + i) * 1024);
        uint4* dst = (uint4*)el;
        if (tid < 128) dst[tid] = src[tid];   // stage full list; tail garbage unread
    }
    __syncthreads();
    int w = tid >> 6, lane = tid & 63;
    for (int c = w; c < 49; c += 4) {       // round-robin cells over 4 waves
        int k = of[c], n = of[c + 1];
        float acc = 0.f;
        for (; k + 8 <= n; k += 8) {        // 8 loads in flight per group
            int j0 = el[k], j1 = el[k + 1], j2 = el[k + 2], j3 = el[k + 3];
            int j4 = el[k + 4], j5 = el[k + 5], j6 = el[k + 6], j7 = el[k + 7];
            float v0 = h_ws[j0 * 64 + lane];
            float v1 = h_ws[j1 * 64 + lane];
            float v2 = h_ws[j2 * 64 + lane];
            float v3 = h_ws[j3 * 64 + lane];
            float v4 = h_ws[j4 * 64 + lane];
            float v5 = h_ws[j5 * 64 + lane];
            float v6 = h_ws[j6 * 64 + lane];
            float v7 = h_ws[j7 * 64 + lane];
            acc += ((v0 + v1) + (v2 + v3)) + ((v4 + v5) + (v6 + v7));
        }
        for (; k < n; k++) acc += h_ws[el[k] * 64 + lane];
        Hbuf[hb_base + c * 64 + lane] = f2b(acc);
    }
}

// ---------------- per step: part[s] = H @ W_soc slice (MFMA, dbuf LDS) -----
// grid 512: ch = bid&3 (64-col slice), s = (bid>>2)&7 (K-split), rb = bid>>5.
// B-tile staged from cell-major Wt2: fully contiguous per cell.
__global__ __launch_bounds__(256) void k_gemm(const unsigned short* __restrict__ Hbuf,
                                              const unsigned short* __restrict__ Wt2,
                                              const int* __restrict__ Tpred,
                                              float* __restrict__ part,
                                              int t) {
    if (t > get_tpred(Tpred)) return;
    int bid = blockIdx.x, tid = threadIdx.x;
    int ch = bid & 3, s = (bid >> 2) & 7, rb = bid >> 5;
    int row0 = rb * 64, col0 = ch * 64;
    int m0 = (49 * s) >> 3, m1 = (49 * (s + 1)) >> 3;   // 6,6,6,6,6,6,6,7 cells
    __shared__ __align__(16) short Asm[2][64 * 72];   // double-buffered
    __shared__ __align__(16) short Bsm[2][64 * 72];
    int w = tid >> 6, lane = tid & 63;
    int wrow = (w & 1) * 32, wcol = (w >> 1) * 32;
    int mrow = lane & 15, q = lane >> 4;
    int row = tid >> 2, seg = tid & 3;
    const unsigned short* Arow = Hbuf + (long)(row0 + row) * 3136;
    const long boff = (long)(col0 + row) * 64;
    f32x4 acc[2][2];
    f32x4 zz = {0.f, 0.f, 0.f, 0.f};
    #pragma unroll
    for (int a = 0; a < 2; a++)
        #pragma unroll
        for (int b = 0; b < 2; b++) acc[a][b] = zz;
    uint4 ra0, ra1, rb0, rb1;
    {   // prologue: load cell m0
        int craw = ((m0 / 7) * 8 + (m0 % 7) + 9);
        const unsigned short* Bc = Wt2 + (long)craw * 16384 + boff;
        ra0 = *(const uint4*)(Arow + m0 * 64 + seg * 8);
        ra1 = *(const uint4*)(Arow + m0 * 64 + (seg + 4) * 8);
        rb0 = *(const uint4*)(Bc + seg * 8);
        rb1 = *(const uint4*)(Bc + (seg + 4) * 8);
        *(uint4*)&Asm[0][row * 72 + seg * 8] = ra0;
        *(uint4*)&Asm[0][row * 72 + (seg + 4) * 8] = ra1;
        *(uint4*)&Bsm[0][row * 72 + seg * 8] = rb0;
        *(uint4*)&Bsm[0][row * 72 + (seg + 4) * 8] = rb1;
    }
    __syncthreads();
    for (int m = m0; m < m1; m++) {
        int p = (m - m0) & 1;
        if (m + 1 < m1) {   // prefetch next cell into the other buffer
            int mm = m + 1;
            int craw = ((mm / 7) * 8 + (mm % 7) + 9);
            const unsigned short* Bc = Wt2 + (long)craw * 16384 + boff;
            ra0 = *(const uint4*)(Arow + mm * 64 + seg * 8);
            ra1 = *(const uint4*)(Arow + mm * 64 + (seg + 4) * 8);
            rb0 = *(const uint4*)(Bc + seg * 8);
            rb1 = *(const uint4*)(Bc + (seg + 4) * 8);
            *(uint4*)&Asm[p ^ 1][row * 72 + seg * 8] = ra0;
            *(uint4*)&Asm[p ^ 1][row * 72 + (seg + 4) * 8] = ra1;
            *(uint4*)&Bsm[p ^ 1][row * 72 + seg * 8] = rb0;
            *(uint4*)&Bsm[p ^ 1][row * 72 + (seg + 4) * 8] = rb1;
        }
        #pragma unroll
        for (int kc = 0; kc < 2; kc++) {
            bf16x8 a0 = *(bf16x8*)&Asm[p][(wrow +      mrow) * 72 + kc * 32 + q * 8];
            bf16x8 a1 = *(bf16x8*)&Asm[p][(wrow + 16 + mrow) * 72 + kc * 32 + q * 8];
            #pragma unroll
            for (int ct = 0; ct < 2; ct++) {
                bf16x8 bv = *(bf16x8*)&Bsm[p][(wcol + ct * 16 + mrow) * 72 + kc * 32 + q * 8];
                acc[0][ct] = __builtin_amdgcn_mfma_f32_16x16x32_bf16(a0, bv, acc[0][ct], 0, 0, 0);
                acc[1][ct] = __builtin_amdgcn_mfma_f32_16x16x32_bf16(a1, bv, acc[1][ct], 0, 0, 0);
            }
        }
        __syncthreads();
    }
    // C/D layout: col = lane&15, row = (lane>>4)*4 + reg. Plain stores, no RMW.
    float* ps = part + (long)s * 262144;
    #pragma unroll
    for (int rt = 0; rt < 2; rt++)
        #pragma unroll
        for (int ct = 0; ct < 2; ct++)
            #pragma unroll
            for (int r = 0; r < 4; r++) {
                int grow = row0 + wrow + rt * 16 + q * 4 + r;
                int gcol = col0 + wcol + ct * 16 + mrow;
                ps[grow * 256 + gcol] = acc[rt][ct][r];
            }
}

// ---------------- per step: gates GEMV (8 rows/block), LSTM cell, out ------
// grid 128 x 512 threads: 8 rows/block, 2-way K-split. Weights read once per
// block (50 MB/step); zT broadcast-read from LDS.
__global__ __launch_bounds__(512) void k_cell(const int* __restrict__ masks,
                                              const void* __restrict__ Y,
                                              const void* __restrict__ bsoc,
                                              const void* __restrict__ Wih,
                                              const void* __restrict__ bih,
                                              const void* __restrict__ Whh,
                                              const void* __restrict__ bhh,
                                              const void* __restrict__ Wout,
                                              const void* __restrict__ bout,
                                              const int* __restrict__ Tpred,
                                              const int* __restrict__ flag,
                                              float* __restrict__ h_ws,
                                              float* __restrict__ c_ws,
                                              const float* __restrict__ r_all,
                                              const float* __restrict__ part,
                                              void* __restrict__ out,
                                              int t) {
    if (t > get_tpred(Tpred)) return;
    int isf32 = flag[0];
    int tid = threadIdx.x;
    int r0 = blockIdx.x * 8;
    __shared__ __align__(32) float zT[384][8];   // z transposed: [k][local row]
    __shared__ float g2[2][8][256];              // K-split partial gates
    // phase A: build zT = [r | e | h] for the block's 8 rows
    for (int idx = tid; idx < 3072; idx += 512) {
        int r = idx / 384, k = idx - r * 384;
        int grow = r0 + r;
        float v;
        if (k < 64) {
            v = r_all[((long)t * 1024 + grow) * 64 + k];
        } else if (k < 320) {
            int col = k - 64;
            const float* pp = part + grow * 256 + col;
            float s0 = pp[0 * 262144] + pp[1 * 262144];
            float s1 = pp[2 * 262144] + pp[3 * 262144];
            float s2 = pp[4 * 262144] + pp[5 * 262144];
            float s3 = pp[6 * 262144] + pp[7 * 262144];
            v = fmaxf(ldin(bsoc, col, isf32) + ((s0 + s1) + (s2 + s3)), 0.f);
        } else {
            v = h_ws[grow * 64 + (k - 320)];
        }
        zT[k][r] = v;
    }
    __syncthreads();
    // phase B: partial gates; each weight element loaded exactly once per block
    int kh = tid >> 8, col = tid & 255;
    float a0 = 0.f, a1 = 0.f, a2 = 0.f, a3 = 0.f,
          a4 = 0.f, a5 = 0.f, a6 = 0.f, a7 = 0.f;
    int klo = kh ? 192 : 0, khi = kh ? 384 : 192;
    #pragma unroll 2
    for (int k = klo; k < khi; k++) {
        float wv;
        if (isf32) {
            wv = (k < 320) ? ((const float*)Wih)[(long)k * 256 + col]
                           : ((const float*)Whh)[(long)(k - 320) * 256 + col];
        } else {
            wv = (k < 320) ? u2f(((const unsigned short*)Wih)[(long)k * 256 + col])
                           : u2f(((const unsigned short*)Whh)[(long)(k - 320) * 256 + col]);
        }
        f32x4 z0 = *(f32x4*)&zT[k][0];
        f32x4 z1 = *(f32x4*)&zT[k][4];
        a0 += z0[0] * wv; a1 += z0[1] * wv; a2 += z0[2] * wv; a3 += z0[3] * wv;
        a4 += z1[0] * wv; a5 += z1[1] * wv; a6 += z1[2] * wv; a7 += z1[3] * wv;
    }
    g2[kh][0][col] = a0; g2[kh][1][col] = a1; g2[kh][2][col] = a2; g2[kh][3][col] = a3;
    g2[kh][4][col] = a4; g2[kh][5][col] = a5; g2[kh][6][col] = a6; g2[kh][7][col] = a7;
    __syncthreads();
    // phase C: fold K-split halves + biases
    if (tid < 256) {
        float bb = ldin(bih, tid, isf32) + ldin(bhh, tid, isf32);
        #pragma unroll
        for (int r = 0; r < 8; r++)
            g2[0][r][tid] = g2[0][r][tid] + g2[1][r][tid] + bb;
    }
    __syncthreads();
    // phase D: LSTM cell + output (8 rows x 64 lanes)
    {
        int row = tid >> 6, u = tid & 63;
        int grow = r0 + row;
        float gi = g2[0][row][u];
        float gf = g2[0][row][64 + u];
        float gg = g2[0][row][128 + u];
        float go = g2[0][row][192 + u];
        float c  = c_ws[grow * 64 + u];
        float si = 1.f / (1.f + __expf(-gi));
        float sf = 1.f / (1.f + __expf(-gf));
        float so = 1.f / (1.f + __expf(-go));
        float cn = sf * c + si * tanhf(gg);
        float hn = so * tanhf(cn);
        c_ws[grow * 64 + u] = cn;
        h_ws[grow * 64 + u] = hn;
        float p0 = hn * ldin(Wout, u * 2 + 0, isf32);
        float p1 = hn * ldin(Wout, u * 2 + 1, isf32);
        #pragma unroll
        for (int o = 32; o >= 1; o >>= 1) {
            p0 += __shfl_xor(p0, o);
            p1 += __shfl_xor(p1, o);
        }
        if (u == 0) {
            int m = masks[t * 1024 + grow];
            float o0 = 0.f, o1 = 0.f;
            if (m != 0) {
                bool appear = (t > 3) && (masks[(t - 3) * 1024 + grow] == 0);
                if (appear) {
                    o0 = ldin(Y, (t * 1024 + grow) * 2 + 0, isf32);
                    o1 = ldin(Y, (t * 1024 + grow) * 2 + 1, isf32);
                } else {
                    o0 = p0 + ldin(bout, 0, isf32);
                    o1 = p1 + ldin(bout, 1, isf32);
                }
            }
            if (!(o0 == o0)) o0 = 0.f;            // sanitize: finite diagnostics
            if (!(o1 == o1)) o1 = 0.f;
            int ofs = (t * 1024 + grow) * 2;
            if (isf32) {
                ((float*)out)[ofs + 0] = o0;
                ((float*)out)[ofs + 1] = o1;
            } else {
                ((unsigned short*)out)[ofs + 0] = f2b(o0);
                ((unsigned short*)out)[ofs + 1] = f2b(o1);
            }
        }
    }
}

extern "C" void kernel_launch(void* const* d_in, const int* in_sizes, int n_in,
                              void* d_out, int out_size, void* d_ws, size_t ws_size,
                              hipStream_t stream) {
    (void)in_sizes; (void)n_in; (void)out_size; (void)ws_size;
    const void* X     = d_in[0];
    const int*  masks = (const int*)d_in[1];
    const void* h0    = d_in[2];
    const void* c0    = d_in[3];
    const void* Y     = d_in[4];
    // d_in[5] = T_obs (unused by reference)
    const int*  Tpred = (const int*)d_in[6];
    const void* Wemb  = d_in[7];
    const void* bemb  = d_in[8];
    const void* Wsoc  = d_in[9];
    const void* bsoc  = d_in[10];
    const void* Wih   = d_in[11];
    const void* bih   = d_in[12];
    const void* Whh   = d_in[13];
    const void* bhh   = d_in[14];
    const void* Wout  = d_in[15];
    const void* bout  = d_in[16];

    char* ws = (char*)d_ws;
    float*          h_ws  = (float*)(ws + 0);
    float*          c_ws  = (float*)(ws + 262144);
    unsigned short* Wt2   = (unsigned short*)(ws + 1835008);
    unsigned short* Hbuf  = (unsigned short*)(ws + 3932160);
    int*            flag  = (int*)(ws + 11141120);
    float*          part  = (float*)(ws + 16777216);
    float*          r_all = (float*)(ws + 33554432);
    unsigned short* offs  = (unsigned short*)(ws + 41943040);
    unsigned short* ents  = (unsigned short*)(ws + 50331648);

    k_detect<<<1, 256, 0, stream>>>(Wsoc, flag);
    k_transpose<<<128, 256, 0, stream>>>(Wsoc, Wt2, flag);
    k_init<<<48, 256, 0, stream>>>(d_out, h0, c0, h_ws, c_ws, flag);
    k_codes<<<32768, 256, 0, stream>>>(X, masks, Wemb, bemb, Tpred, flag,
                                       r_all, offs, ents);
    for (int t = 0; t < 32; t++) {
        k_pool<<<1024, 256, 0, stream>>>(masks, Tpred, h_ws, offs, ents, Hbuf, t);
        k_gemm<<<512, 256, 0, stream>>>(Hbuf, Wt2, Tpred, part, t);
        k_cell<<<128, 512, 0, stream>>>(masks, Y, bsoc, Wih, bih, Whh, bhh,
                                        Wout, bout, Tpred, flag, h_ws, c_ws,
                                        r_all, part, d_out, t);
    }
}

// Round 4
// 1076.922 us; speedup vs baseline: 2.7434x; 1.7514x over previous
//
#include <hip/hip_runtime.h>
#include <hip/hip_bf16.h>

// SocialLSTM forward, MI355X gfx950.
// Dual-dtype: float inputs may be bf16 or f32; detected at runtime from W_soc.
// ws layout (bytes):
//   h_ws  f32[1024*64]      @ 0
//   c_ws  f32[1024*64]      @ 262144
//   Wt2   bf16[64][256][64] @ 1835008   (W_soc cell-major: [cell][n][k], 2 MB)
//   Hbuf  bf16[1024*3136]   @ 3932160   (49 reachable cells * 64 hid per row)
//   flag  int32             @ 11141120  (0 = bf16 inputs, 1 = f32 inputs)
//   part  f32[8][1024*256]  @ 16777216  (K-split GEMM partials, no atomics)
//   r_all f32[32][1024][64] @ 33554432  (precomputed r = relu(coords@Wemb+b))
//   offs  u16[32*1024][64]  @ 41943040  (per (t,i): 50 prefix offsets of cell lists)
//   ents  u16[32*1024][1024]@ 50331648  (per (t,i): compacted neighbor j-lists)

typedef short bf16x8 __attribute__((ext_vector_type(8)));
typedef float f32x4 __attribute__((ext_vector_type(4)));

__device__ __forceinline__ float u2f(unsigned short u) {
    union { unsigned int i; float f; } v; v.i = ((unsigned int)u) << 16; return v.f;
}
__device__ __forceinline__ unsigned short f2b(float f) {
    __hip_bfloat16 hb = __float2bfloat16(f);
    return *(unsigned short*)&hb;
}
__device__ __forceinline__ float ldin(const void* p, int idx, int isf32) {
    return isf32 ? ((const float*)p)[idx] : u2f(((const unsigned short*)p)[idx]);
}
__device__ __forceinline__ int get_tpred(const int* p) {
    int v = p[0];
    if (v >= 0 && v <= 64) return v;
    float f = ((const float*)p)[0];
    if (f >= 0.f && f <= 64.f) return (int)f;
    float g = u2f(((const unsigned short*)p)[0]);
    if (g >= 0.f && g <= 64.f) return (int)g;
    return 31;
}

// ---------------- dtype detector: bf16-decode W_soc, look for huge/NaN -----
__global__ __launch_bounds__(256) void k_detect(const void* __restrict__ Wsoc,
                                                int* __restrict__ flag) {
    __shared__ int f;
    int tid = threadIdx.x;
    if (tid == 0) f = 0;
    __syncthreads();
    const unsigned short* p = (const unsigned short*)Wsoc;
    #pragma unroll
    for (int k = 0; k < 4; k++) {
        float v = u2f(p[tid * 4 + k]);
        if (!(v == v) || fabsf(v) > 1e20f) f = 1;   // same-address LDS write, benign
    }
    __syncthreads();
    if (tid == 0) flag[0] = f;
}

// ------- one-time: W_soc (4096x256) -> Wt2 bf16 cell-major [cell][n][k] ----
__global__ __launch_bounds__(256) void k_transpose(const void* __restrict__ Wsoc,
                                                   unsigned short* __restrict__ Wt2,
                                                   const int* __restrict__ flag) {
    __shared__ __align__(16) unsigned short tile[32 * 264];
    int isf32 = flag[0];
    int b = blockIdx.x, tid = threadIdx.x;
    int k0 = b * 32;
    if (isf32) {
        const float* W = (const float*)Wsoc;
        #pragma unroll
        for (int p = 0; p < 4; p++) {
            int kk = (tid >> 5) + p * 8;
            int n8 = (tid & 31) * 8;
            #pragma unroll
            for (int q = 0; q < 8; q++)
                tile[kk * 264 + n8 + q] = f2b(W[(k0 + kk) * 256 + n8 + q]);
        }
    } else {
        const unsigned short* W = (const unsigned short*)Wsoc;
        #pragma unroll
        for (int p = 0; p < 4; p++) {
            int kk = (tid >> 5) + p * 8;
            int n8 = (tid & 31) * 8;
            *(uint4*)&tile[kk * 264 + n8] = *(const uint4*)(W + (k0 + kk) * 256 + n8);
        }
    }
    __syncthreads();
    int n = tid;
    unsigned int packed[16];
    #pragma unroll
    for (int q = 0; q < 16; q++) {
        unsigned int lo = tile[(2 * q) * 264 + n];
        unsigned int hi = tile[(2 * q + 1) * 264 + n];
        packed[q] = lo | (hi << 16);
    }
    int craw = k0 >> 6, kk0 = k0 & 63;
    uint4* dst = (uint4*)(Wt2 + (long)craw * 16384 + (long)n * 64 + kk0);
    #pragma unroll
    for (int p = 0; p < 4; p++)
        dst[p] = make_uint4(packed[4*p], packed[4*p+1], packed[4*p+2], packed[4*p+3]);
}

// ---------------- one-time: zero d_out (dtype-sized), h0/c0 -> f32 ---------
__global__ __launch_bounds__(256) void k_init(void* __restrict__ out,
                                              const void* __restrict__ hin,
                                              const void* __restrict__ cin,
                                              float* __restrict__ h_ws,
                                              float* __restrict__ c_ws,
                                              const int* __restrict__ flag) {
    int isf32 = flag[0];
    int b = blockIdx.x, tid = threadIdx.x;
    if (b < 16) {
        uint4 z = make_uint4(0u, 0u, 0u, 0u);
        uint4* p = (uint4*)out;
        int n16 = isf32 ? 16384 : 8192;          // 65536 elems * 4 or 2 bytes / 16
        for (int idx = b * 256 + tid; idx < n16; idx += 4096) p[idx] = z;
    } else {
        int sb = b - 16;
        const void* src = (sb < 16) ? hin : cin;
        float* dst = (sb < 16) ? h_ws : c_ws;
        sb &= 15;
        int base = (sb * 256 + tid) * 16;
        #pragma unroll
        for (int p = 0; p < 16; p++) dst[base + p] = ldin(src, base + p, isf32);
    }
}

// ---------------- one-time: codes via LDS-atomic ranks + r_all -------------
// grid 32*1024 blocks: t = bid>>10, i = bid&1023. 4 LDS atomics + scatter
// replaces the 2-pass ballot compaction (155 -> 48 us, verified round 3).
__global__ __launch_bounds__(256) void k_codes(const void* __restrict__ X,
                                               const int* __restrict__ masks,
                                               const void* __restrict__ Wemb,
                                               const void* __restrict__ bemb,
                                               const int* __restrict__ Tpred,
                                               const int* __restrict__ flag,
                                               float* __restrict__ r_all,
                                               unsigned short* __restrict__ offs,
                                               unsigned short* __restrict__ ents) {
    int bid = blockIdx.x;
    int t = bid >> 10, i = bid & 1023;
    if (t > get_tpred(Tpred)) return;
    int isf32 = flag[0];
    int tid = threadIdx.x;
    __shared__ int cnt[49];
    __shared__ unsigned short off_s[52];
    float cix, ciy;
    if (isf32) {
        const float* Xf = (const float*)X;
        cix = Xf[(t * 1024 + i) * 4 + 2];
        ciy = Xf[(t * 1024 + i) * 4 + 3];
    } else {
        const unsigned short* Xb = (const unsigned short*)X;
        cix = u2f(Xb[(t * 1024 + i) * 4 + 2]);
        ciy = u2f(Xb[(t * 1024 + i) * 4 + 3]);
    }
    if (tid < 64) {
        float v = ldin(Wemb, tid, isf32) * cix + ldin(Wemb, 64 + tid, isf32) * ciy
                + ldin(bemb, tid, isf32);
        r_all[((long)t * 1024 + i) * 64 + tid] = fmaxf(v, 0.f);
    }
    if (masks[t * 1024 + i] == 0) return;     // block-uniform; lists unused
    if (tid < 49) cnt[tid] = 0;
    __syncthreads();
    int cc[4], rk[4];
    #pragma unroll
    for (int p = 0; p < 4; p++) {
        int j = tid + p * 256;
        cc[p] = -1;
        if (j != i && masks[t * 1024 + j] != 0) {
            float dx, dy;
            if (isf32) {
                const float* Xf = (const float*)X;
                dx = Xf[(t * 1024 + j) * 4 + 2] - cix;
                dy = Xf[(t * 1024 + j) * 4 + 3] - ciy;
            } else {
                const unsigned short* Xb = (const unsigned short*)X;
                dx = u2f(Xb[(t * 1024 + j) * 4 + 2]) - cix;
                dy = u2f(Xb[(t * 1024 + j) * 4 + 3]) - ciy;
            }
            int g0 = (int)dx, g1 = (int)dy;   // trunc toward zero == jnp.trunc
            if (g0 >= -3 && g0 <= 3 && g1 >= -3 && g1 <= 3) {
                int c = (g0 + 3) * 7 + (g1 + 3);      // dense 0..48
                cc[p] = c;
                rk[p] = atomicAdd(&cnt[c], 1);
            }
        }
    }
    __syncthreads();
    if (tid == 0) {
        int o = 0;
        #pragma unroll 1
        for (int c = 0; c < 49; c++) { off_s[c] = (unsigned short)o; o += cnt[c]; }
        off_s[49] = (unsigned short)o;
    }
    __syncthreads();
    unsigned short* eb = ents + ((long)t * 1024 + i) * 1024;
    #pragma unroll
    for (int p = 0; p < 4; p++)
        if (cc[p] >= 0)
            eb[off_s[cc[p]] + rk[p]] = (unsigned short)(tid + p * 256);
    if (tid < 50) offs[((long)t * 1024 + i) * 64 + tid] = off_s[tid];
}

// ---------------- per step: pure gather-accumulate pooling -> Hbuf ---------
// 1024 blocks (one per agent) keeps ~16 waves/CU of independent gather work
// in flight — this phase is latency-bound, parallelism is the currency.
__global__ __launch_bounds__(256) void k_pool(const int* __restrict__ masks,
                                              const int* __restrict__ Tpred,
                                              const float* __restrict__ h_ws,
                                              const unsigned short* __restrict__ offs,
                                              const unsigned short* __restrict__ ents,
                                              unsigned short* __restrict__ Hbuf,
                                              int t) {
    if (t > get_tpred(Tpred)) return;
    int i = blockIdx.x, tid = threadIdx.x;
    long hb_base = (long)i * 3136;
    if (masks[t * 1024 + i] == 0) {   // block-uniform: H row is all zeros
        unsigned int* hp = (unsigned int*)(Hbuf + hb_base);
        for (int idx = tid; idx < 1568; idx += 256) hp[idx] = 0u;
        return;
    }
    __shared__ __align__(16) unsigned short el[1024];
    __shared__ unsigned short of[52];
    if (tid < 50) of[tid] = offs[((long)t * 1024 + i) * 64 + tid];
    {
        const uint4* src = (const uint4*)(ents + ((long)t * 1024 + i) * 1024);
        uint4* dst = (uint4*)el;
        if (tid < 128) dst[tid] = src[tid];   // stage full list; tail garbage unread
    }
    __syncthreads();
    int w = tid >> 6, lane = tid & 63;
    for (int c = w; c < 49; c += 4) {       // round-robin cells over 4 waves
        int k = of[c], n = of[c + 1];
        float acc = 0.f;
        for (; k + 8 <= n; k += 8) {        // 8 loads in flight per group
            int j0 = el[k], j1 = el[k + 1], j2 = el[k + 2], j3 = el[k + 3];
            int j4 = el[k + 4], j5 = el[k + 5], j6 = el[k + 6], j7 = el[k + 7];
            float v0 = h_ws[j0 * 64 + lane];
            float v1 = h_ws[j1 * 64 + lane];
            float v2 = h_ws[j2 * 64 + lane];
            float v3 = h_ws[j3 * 64 + lane];
            float v4 = h_ws[j4 * 64 + lane];
            float v5 = h_ws[j5 * 64 + lane];
            float v6 = h_ws[j6 * 64 + lane];
            float v7 = h_ws[j7 * 64 + lane];
            acc += ((v0 + v1) + (v2 + v3)) + ((v4 + v5) + (v6 + v7));
        }
        for (; k < n; k++) acc += h_ws[el[k] * 64 + lane];
        Hbuf[hb_base + c * 64 + lane] = f2b(acc);
    }
}

// ---------------- per step: part[s] = H @ W_soc slice (MFMA, dbuf LDS) -----
// grid 512: ch = bid&3 (64-col slice), s = (bid>>2)&7 (K-split), rb = bid>>5.
// B-tile staged from cell-major Wt2: fully contiguous per cell.
__global__ __launch_bounds__(256) void k_gemm(const unsigned short* __restrict__ Hbuf,
                                              const unsigned short* __restrict__ Wt2,
                                              const int* __restrict__ Tpred,
                                              float* __restrict__ part,
                                              int t) {
    if (t > get_tpred(Tpred)) return;
    int bid = blockIdx.x, tid = threadIdx.x;
    int ch = bid & 3, s = (bid >> 2) & 7, rb = bid >> 5;
    int row0 = rb * 64, col0 = ch * 64;
    int m0 = (49 * s) >> 3, m1 = (49 * (s + 1)) >> 3;   // 6,6,6,6,6,6,6,7 cells
    __shared__ __align__(16) short Asm[2][64 * 72];   // double-buffered
    __shared__ __align__(16) short Bsm[2][64 * 72];
    int w = tid >> 6, lane = tid & 63;
    int wrow = (w & 1) * 32, wcol = (w >> 1) * 32;
    int mrow = lane & 15, q = lane >> 4;
    int row = tid >> 2, seg = tid & 3;
    const unsigned short* Arow = Hbuf + (long)(row0 + row) * 3136;
    const long boff = (long)(col0 + row) * 64;
    f32x4 acc[2][2];
    f32x4 zz = {0.f, 0.f, 0.f, 0.f};
    #pragma unroll
    for (int a = 0; a < 2; a++)
        #pragma unroll
        for (int b = 0; b < 2; b++) acc[a][b] = zz;
    uint4 ra0, ra1, rb0, rb1;
    {   // prologue: load cell m0
        int craw = ((m0 / 7) * 8 + (m0 % 7) + 9);
        const unsigned short* Bc = Wt2 + (long)craw * 16384 + boff;
        ra0 = *(const uint4*)(Arow + m0 * 64 + seg * 8);
        ra1 = *(const uint4*)(Arow + m0 * 64 + (seg + 4) * 8);
        rb0 = *(const uint4*)(Bc + seg * 8);
        rb1 = *(const uint4*)(Bc + (seg + 4) * 8);
        *(uint4*)&Asm[0][row * 72 + seg * 8] = ra0;
        *(uint4*)&Asm[0][row * 72 + (seg + 4) * 8] = ra1;
        *(uint4*)&Bsm[0][row * 72 + seg * 8] = rb0;
        *(uint4*)&Bsm[0][row * 72 + (seg + 4) * 8] = rb1;
    }
    __syncthreads();
    for (int m = m0; m < m1; m++) {
        int p = (m - m0) & 1;
        if (m + 1 < m1) {   // prefetch next cell into the other buffer
            int mm = m + 1;
            int craw = ((mm / 7) * 8 + (mm % 7) + 9);
            const unsigned short* Bc = Wt2 + (long)craw * 16384 + boff;
            ra0 = *(const uint4*)(Arow + mm * 64 + seg * 8);
            ra1 = *(const uint4*)(Arow + mm * 64 + (seg + 4) * 8);
            rb0 = *(const uint4*)(Bc + seg * 8);
            rb1 = *(const uint4*)(Bc + (seg + 4) * 8);
            *(uint4*)&Asm[p ^ 1][row * 72 + seg * 8] = ra0;
            *(uint4*)&Asm[p ^ 1][row * 72 + (seg + 4) * 8] = ra1;
            *(uint4*)&Bsm[p ^ 1][row * 72 + seg * 8] = rb0;
            *(uint4*)&Bsm[p ^ 1][row * 72 + (seg + 4) * 8] = rb1;
        }
        #pragma unroll
        for (int kc = 0; kc < 2; kc++) {
            bf16x8 a0 = *(bf16x8*)&Asm[p][(wrow +      mrow) * 72 + kc * 32 + q * 8];
            bf16x8 a1 = *(bf16x8*)&Asm[p][(wrow + 16 + mrow) * 72 + kc * 32 + q * 8];
            #pragma unroll
            for (int ct = 0; ct < 2; ct++) {
                bf16x8 bv = *(bf16x8*)&Bsm[p][(wcol + ct * 16 + mrow) * 72 + kc * 32 + q * 8];
                acc[0][ct] = __builtin_amdgcn_mfma_f32_16x16x32_bf16(a0, bv, acc[0][ct], 0, 0, 0);
                acc[1][ct] = __builtin_amdgcn_mfma_f32_16x16x32_bf16(a1, bv, acc[1][ct], 0, 0, 0);
            }
        }
        __syncthreads();
    }
    // C/D layout: col = lane&15, row = (lane>>4)*4 + reg. Plain stores, no RMW.
    float* ps = part + (long)s * 262144;
    #pragma unroll
    for (int rt = 0; rt < 2; rt++)
        #pragma unroll
        for (int ct = 0; ct < 2; ct++)
            #pragma unroll
            for (int r = 0; r < 4; r++) {
                int grow = row0 + wrow + rt * 16 + q * 4 + r;
                int gcol = col0 + wcol + ct * 16 + mrow;
                ps[grow * 256 + gcol] = acc[rt][ct][r];
            }
}

// ---------------- per step: gates GEMV, LSTM cell, out ---------------------
// grid 256 x 1024 threads: 4 rows/block, 4-way K-split (96 k-iters each).
// 16 waves/CU (2x round-1) + unroll-8 load pipelining: latency-bound phase,
// parallelism is the currency. Weights L2-resident; read once per block.
__global__ __launch_bounds__(1024) void k_cell(const int* __restrict__ masks,
                                               const void* __restrict__ Y,
                                               const void* __restrict__ bsoc,
                                               const void* __restrict__ Wih,
                                               const void* __restrict__ bih,
                                               const void* __restrict__ Whh,
                                               const void* __restrict__ bhh,
                                               const void* __restrict__ Wout,
                                               const void* __restrict__ bout,
                                               const int* __restrict__ Tpred,
                                               const int* __restrict__ flag,
                                               float* __restrict__ h_ws,
                                               float* __restrict__ c_ws,
                                               const float* __restrict__ r_all,
                                               const float* __restrict__ part,
                                               void* __restrict__ out,
                                               int t) {
    if (t > get_tpred(Tpred)) return;
    int isf32 = flag[0];
    int tid = threadIdx.x;
    int r0 = blockIdx.x * 4;
    __shared__ __align__(16) float zT[384][4];   // z transposed: [k][local row]
    __shared__ float g2[4][4][256];              // [ksplit][row][col] partials
    // phase A: build zT = [r | e | h] for the block's 4 rows
    for (int idx = tid; idx < 1536; idx += 1024) {
        int r = idx / 384, k = idx - r * 384;
        int grow = r0 + r;
        float v;
        if (k < 64) {
            v = r_all[((long)t * 1024 + grow) * 64 + k];
        } else if (k < 320) {
            int col = k - 64;
            const float* pp = part + grow * 256 + col;
            float s0 = pp[0 * 262144] + pp[1 * 262144];
            float s1 = pp[2 * 262144] + pp[3 * 262144];
            float s2 = pp[4 * 262144] + pp[5 * 262144];
            float s3 = pp[6 * 262144] + pp[7 * 262144];
            v = fmaxf(ldin(bsoc, col, isf32) + ((s0 + s1) + (s2 + s3)), 0.f);
        } else {
            v = h_ws[grow * 64 + (k - 320)];
        }
        zT[k][r] = v;
    }
    __syncthreads();
    // phase B: partial gates; dtype branch hoisted, unroll-8 load pipelining
    int kh = tid >> 8, col = tid & 255;
    int klo = kh * 96, khi = klo + 96;
    float a0 = 0.f, a1 = 0.f, a2 = 0.f, a3 = 0.f;
    if (isf32) {
        const float* W1 = (const float*)Wih;
        const float* W2 = (const float*)Whh;
        int kmid = khi < 320 ? khi : 320;
        #pragma unroll 8
        for (int k = klo; k < kmid; k++) {
            float wv = W1[(long)k * 256 + col];
            f32x4 zv = *(f32x4*)&zT[k][0];
            a0 += zv[0] * wv; a1 += zv[1] * wv; a2 += zv[2] * wv; a3 += zv[3] * wv;
        }
        int k2 = klo > 320 ? klo : 320;
        #pragma unroll 8
        for (int k = k2; k < khi; k++) {
            float wv = W2[(long)(k - 320) * 256 + col];
            f32x4 zv = *(f32x4*)&zT[k][0];
            a0 += zv[0] * wv; a1 += zv[1] * wv; a2 += zv[2] * wv; a3 += zv[3] * wv;
        }
    } else {
        const unsigned short* W1 = (const unsigned short*)Wih;
        const unsigned short* W2 = (const unsigned short*)Whh;
        int kmid = khi < 320 ? khi : 320;
        #pragma unroll 8
        for (int k = klo; k < kmid; k++) {
            float wv = u2f(W1[(long)k * 256 + col]);
            f32x4 zv = *(f32x4*)&zT[k][0];
            a0 += zv[0] * wv; a1 += zv[1] * wv; a2 += zv[2] * wv; a3 += zv[3] * wv;
        }
        int k2 = klo > 320 ? klo : 320;
        #pragma unroll 8
        for (int k = k2; k < khi; k++) {
            float wv = u2f(W2[(long)(k - 320) * 256 + col]);
            f32x4 zv = *(f32x4*)&zT[k][0];
            a0 += zv[0] * wv; a1 += zv[1] * wv; a2 += zv[2] * wv; a3 += zv[3] * wv;
        }
    }
    g2[kh][0][col] = a0; g2[kh][1][col] = a1;
    g2[kh][2][col] = a2; g2[kh][3][col] = a3;
    __syncthreads();
    // phase C: fold 4 K-split partials + biases
    if (tid < 256) {
        float bb = ldin(bih, tid, isf32) + ldin(bhh, tid, isf32);
        #pragma unroll
        for (int r = 0; r < 4; r++)
            g2[0][r][tid] = ((g2[0][r][tid] + g2[1][r][tid])
                           + (g2[2][r][tid] + g2[3][r][tid])) + bb;
    }
    __syncthreads();
    // phase D: LSTM cell + output (4 rows x 64 lanes)
    if (tid < 256) {
        int row = tid >> 6, u = tid & 63;
        int grow = r0 + row;
        float gi = g2[0][row][u];
        float gf = g2[0][row][64 + u];
        float gg = g2[0][row][128 + u];
        float go = g2[0][row][192 + u];
        float c  = c_ws[grow * 64 + u];
        float si = 1.f / (1.f + __expf(-gi));
        float sf = 1.f / (1.f + __expf(-gf));
        float so = 1.f / (1.f + __expf(-go));
        float cn = sf * c + si * tanhf(gg);
        float hn = so * tanhf(cn);
        c_ws[grow * 64 + u] = cn;
        h_ws[grow * 64 + u] = hn;
        float p0 = hn * ldin(Wout, u * 2 + 0, isf32);
        float p1 = hn * ldin(Wout, u * 2 + 1, isf32);
        #pragma unroll
        for (int o = 32; o >= 1; o >>= 1) {
            p0 += __shfl_xor(p0, o);
            p1 += __shfl_xor(p1, o);
        }
        if (u == 0) {
            int m = masks[t * 1024 + grow];
            float o0 = 0.f, o1 = 0.f;
            if (m != 0) {
                bool appear = (t > 3) && (masks[(t - 3) * 1024 + grow] == 0);
                if (appear) {
                    o0 = ldin(Y, (t * 1024 + grow) * 2 + 0, isf32);
                    o1 = ldin(Y, (t * 1024 + grow) * 2 + 1, isf32);
                } else {
                    o0 = p0 + ldin(bout, 0, isf32);
                    o1 = p1 + ldin(bout, 1, isf32);
                }
            }
            if (!(o0 == o0)) o0 = 0.f;            // sanitize: finite diagnostics
            if (!(o1 == o1)) o1 = 0.f;
            int ofs = (t * 1024 + grow) * 2;
            if (isf32) {
                ((float*)out)[ofs + 0] = o0;
                ((float*)out)[ofs + 1] = o1;
            } else {
                ((unsigned short*)out)[ofs + 0] = f2b(o0);
                ((unsigned short*)out)[ofs + 1] = f2b(o1);
            }
        }
    }
}

extern "C" void kernel_launch(void* const* d_in, const int* in_sizes, int n_in,
                              void* d_out, int out_size, void* d_ws, size_t ws_size,
                              hipStream_t stream) {
    (void)in_sizes; (void)n_in; (void)out_size; (void)ws_size;
    const void* X     = d_in[0];
    const int*  masks = (const int*)d_in[1];
    const void* h0    = d_in[2];
    const void* c0    = d_in[3];
    const void* Y     = d_in[4];
    // d_in[5] = T_obs (unused by reference)
    const int*  Tpred = (const int*)d_in[6];
    const void* Wemb  = d_in[7];
    const void* bemb  = d_in[8];
    const void* Wsoc  = d_in[9];
    const void* bsoc  = d_in[10];
    const void* Wih   = d_in[11];
    const void* bih   = d_in[12];
    const void* Whh   = d_in[13];
    const void* bhh   = d_in[14];
    const void* Wout  = d_in[15];
    const void* bout  = d_in[16];

    char* ws = (char*)d_ws;
    float*          h_ws  = (float*)(ws + 0);
    float*          c_ws  = (float*)(ws + 262144);
    unsigned short* Wt2   = (unsigned short*)(ws + 1835008);
    unsigned short* Hbuf  = (unsigned short*)(ws + 3932160);
    int*            flag  = (int*)(ws + 11141120);
    float*          part  = (float*)(ws + 16777216);
    float*          r_all = (float*)(ws + 33554432);
    unsigned short* offs  = (unsigned short*)(ws + 41943040);
    unsigned short* ents  = (unsigned short*)(ws + 50331648);

    k_detect<<<1, 256, 0, stream>>>(Wsoc, flag);
    k_transpose<<<128, 256, 0, stream>>>(Wsoc, Wt2, flag);
    k_init<<<48, 256, 0, stream>>>(d_out, h0, c0, h_ws, c_ws, flag);
    k_codes<<<32768, 256, 0, stream>>>(X, masks, Wemb, bemb, Tpred, flag,
                                       r_all, offs, ents);
    for (int t = 0; t < 32; t++) {
        k_pool<<<1024, 256, 0, stream>>>(masks, Tpred, h_ws, offs, ents, Hbuf, t);
        k_gemm<<<512, 256, 0, stream>>>(Hbuf, Wt2, Tpred, part, t);
        k_cell<<<256, 1024, 0, stream>>>(masks, Y, bsoc, Wih, bih, Whh, bhh,
                                         Wout, bout, Tpred, flag, h_ws, c_ws,
                                         r_all, part, d_out, t);
    }
}